// Round 6
// baseline (3036.586 us; speedup 1.0000x reference)
//
#include <hip/hip_runtime.h>
#include <hip/hip_bf16.h>
#include <math.h>

#define LAYERS 8
#define DMODEL 1024
#define NHEAD  16
#define HDIM   64
#define BATCH  2
#define SEQ    1024
#define FFDIM  4096
#define ROWS   (BATCH*SEQ)   // 2048 token rows

using s16x8 = __attribute__((ext_vector_type(8))) short;
using f32x4 = __attribute__((ext_vector_type(4))) float;

__device__ __forceinline__ short f2bf(float f) {
    union { float f; unsigned u; } v; v.f = f;
    unsigned r = v.u + 0x7fffu + ((v.u >> 16) & 1u);   // RNE
    return (short)(r >> 16);
}

// ---------------- fp32 -> bf16 bulk convert (weights, once per call) ----------------
__global__ __launch_bounds__(256) void cvt_kernel(const float* __restrict__ in,
                                                  short* __restrict__ out, int n) {
    int i = (blockIdx.x * 256 + threadIdx.x) * 8;
    if (i >= n) return;
    float4 a = *(const float4*)(in + i);
    float4 b = *(const float4*)(in + i + 4);
    s16x8 o;
    o[0]=f2bf(a.x); o[1]=f2bf(a.y); o[2]=f2bf(a.z); o[3]=f2bf(a.w);
    o[4]=f2bf(b.x); o[5]=f2bf(b.y); o[6]=f2bf(b.z); o[7]=f2bf(b.w);
    *(s16x8*)(out + i) = o;
}

// ---------------- positional encoding: x_ws = x_in + PE ----------------
__global__ __launch_bounds__(256) void posenc_kernel(const float* __restrict__ xin,
                                                     float* __restrict__ xout) {
    int idx = blockIdx.x * 256 + threadIdx.x;           // [0, ROWS*DMODEL)
    int d = idx & (DMODEL - 1);
    int t = (idx >> 10) & (SEQ - 1);
    float e = (float)(2 * (d >> 1)) * (1.0f / DMODEL);
    float rate = expf(-e * 9.210340371976184f);         // 10000^-e
    float a = (float)t * rate;
    float pe = (d & 1) ? cosf(a) : sinf(a);
    xout[idx] = xin[idx] + pe;
}

// ---------------- layernorm: fp32 in -> bf16 out ----------------
__global__ __launch_bounds__(256) void ln_kernel(const float* __restrict__ x,
                                                 const float* __restrict__ g,
                                                 const float* __restrict__ b,
                                                 short* __restrict__ out) {
    int row = blockIdx.x;
    const float* xr = x + (size_t)row * DMODEL;
    int tid = threadIdx.x;
    int d = tid * 4;
    float4 v = *(const float4*)&xr[d];
    float s  = v.x + v.y + v.z + v.w;
    float ss = v.x*v.x + v.y*v.y + v.z*v.z + v.w*v.w;
    #pragma unroll
    for (int off = 32; off >= 1; off >>= 1) {
        s  += __shfl_xor(s, off);
        ss += __shfl_xor(ss, off);
    }
    __shared__ float red[8];
    int wid = tid >> 6, lane = tid & 63;
    if (lane == 0) { red[wid] = s; red[4 + wid] = ss; }
    __syncthreads();
    s  = red[0] + red[1] + red[2] + red[3];
    ss = red[4] + red[5] + red[6] + red[7];
    float mu   = s * (1.0f / DMODEL);
    float var  = ss * (1.0f / DMODEL) - mu * mu;
    float rstd = rsqrtf(var + 1e-5f);
    short4 o;
    o.x = f2bf((v.x - mu) * rstd * g[d+0] + b[d+0]);
    o.y = f2bf((v.y - mu) * rstd * g[d+1] + b[d+1]);
    o.z = f2bf((v.z - mu) * rstd * g[d+2] + b[d+2]);
    o.w = f2bf((v.w - mu) * rstd * g[d+3] + b[d+3]);
    *(short4*)&out[(size_t)row * DMODEL + d] = o;
}

// ---------------- GEMM-BT: out[M,N] = A[M,K](bf16) . W[N,K]^T + bias ----------------
#define EPI_QKV   0
#define EPI_RESID 1
#define EPI_GELU  2
#define EPI_HEAD  3

template<int EPI, bool WBF>
__global__ __launch_bounds__(256)
void gemm_bt(const short* __restrict__ A, const void* __restrict__ Wp,
             const float* __restrict__ bias, const float* __restrict__ resid,
             void* __restrict__ outp, int N, int K) {
    __shared__ short lds_a[128 * 32];
    __shared__ short lds_w[128 * 32];
    int tid  = threadIdx.x;
    int lane = tid & 63, wid = tid >> 6;
    int wr = wid >> 1, wc = wid & 1;                 // wave -> 64x64 quadrant
    int ml = lane & 15, kg = (lane >> 4) * 8;
    int m0 = blockIdx.y * 128, n0 = blockIdx.x * 128;
    int srow = tid >> 1, shalf = tid & 1;            // staging: 2 threads/row, 16 elems each

    f32x4 acc[4][4] = {};

    const short* Abase = A + (size_t)(m0 + srow) * K + shalf * 16;
    short* la = &lds_a[srow * 32 + shalf * 16];
    short* lw = &lds_w[srow * 32 + shalf * 16];

    const short* Wb = WBF ? ((const short*)Wp + (size_t)(n0 + srow) * K + shalf * 16) : nullptr;
    const float* Wf = WBF ? nullptr : ((const float*)Wp + (size_t)(n0 + srow) * K + shalf * 16);

    int nk = K >> 5;
    for (int kt = 0; kt < nk; ++kt) {
        *(s16x8*)la       = *(const s16x8*)(Abase + kt * 32);
        *(s16x8*)(la + 8) = *(const s16x8*)(Abase + kt * 32 + 8);
        if constexpr (WBF) {
            *(s16x8*)lw       = *(const s16x8*)(Wb + kt * 32);
            *(s16x8*)(lw + 8) = *(const s16x8*)(Wb + kt * 32 + 8);
        } else {
            float4 w0 = *(const float4*)(Wf + kt * 32 + 0);
            float4 w1 = *(const float4*)(Wf + kt * 32 + 4);
            float4 w2 = *(const float4*)(Wf + kt * 32 + 8);
            float4 w3 = *(const float4*)(Wf + kt * 32 + 12);
            s16x8 wv;
            wv[0]=f2bf(w0.x); wv[1]=f2bf(w0.y); wv[2]=f2bf(w0.z); wv[3]=f2bf(w0.w);
            wv[4]=f2bf(w1.x); wv[5]=f2bf(w1.y); wv[6]=f2bf(w1.z); wv[7]=f2bf(w1.w);
            *(s16x8*)lw = wv;
            wv[0]=f2bf(w2.x); wv[1]=f2bf(w2.y); wv[2]=f2bf(w2.z); wv[3]=f2bf(w2.w);
            wv[4]=f2bf(w3.x); wv[5]=f2bf(w3.y); wv[6]=f2bf(w3.z); wv[7]=f2bf(w3.w);
            *(s16x8*)(lw + 8) = wv;
        }
        __syncthreads();

        s16x8 af[4], bf[4];
        #pragma unroll
        for (int i = 0; i < 4; i++)
            af[i] = *(const s16x8*)&lds_a[(wr * 64 + i * 16 + ml) * 32 + kg];
        #pragma unroll
        for (int i = 0; i < 4; i++)
            bf[i] = *(const s16x8*)&lds_w[(wc * 64 + i * 16 + ml) * 32 + kg];
        #pragma unroll
        for (int i = 0; i < 4; i++)
            #pragma unroll
            for (int j = 0; j < 4; j++)
                acc[i][j] = __builtin_amdgcn_mfma_f32_16x16x32_bf16(af[i], bf[j], acc[i][j], 0, 0, 0);
        __syncthreads();
    }

    #pragma unroll
    for (int i = 0; i < 4; i++) {
        #pragma unroll
        for (int j = 0; j < 4; j++) {
            #pragma unroll
            for (int r = 0; r < 4; r++) {
                int row = m0 + wr * 64 + i * 16 + (lane >> 4) * 4 + r;
                int col = n0 + wc * 64 + j * 16 + ml;
                float val = acc[i][j][r];
                if constexpr (EPI != EPI_HEAD) val += bias[col];
                if constexpr (EPI == EPI_QKV) {
                    int bb = row >> 10, t = row & (SEQ - 1);
                    int hh = col >> 6,  dd = col & (HDIM - 1);
                    ((short*)outp)[(((size_t)bb * NHEAD + hh) * SEQ + t) * HDIM + dd] = f2bf(val);
                } else if constexpr (EPI == EPI_RESID) {
                    size_t o = (size_t)row * N + col;
                    ((float*)outp)[o] = resid[o] + val;
                } else if constexpr (EPI == EPI_GELU) {
                    float ge = 0.5f * val * (1.0f + erff(val * 0.70710678118654752f));
                    ((short*)outp)[(size_t)row * N + col] = f2bf(ge);
                } else { // HEAD
                    ((float*)outp)[(size_t)row * N + col] = val;
                }
            }
        }
    }
}

// ---------------- causal flash attention ----------------
__global__ __launch_bounds__(256)
void attn_kernel(const short* __restrict__ q, const short* __restrict__ kp,
                 const short* __restrict__ v, short* __restrict__ y) {
    __shared__ short lds_k[64 * 64];     // [t][d]
    __shared__ short lds_vt[64 * 64];    // [d][t]
    __shared__ short lds_p[4][16 * 64];  // per-wave P tile [q][t]
    int tid  = threadIdx.x;
    int lane = tid & 63, wid = tid >> 6;
    int ml = lane & 15, kg = (lane >> 4) * 8;
    int qt = blockIdx.x, bh = blockIdx.y;
    size_t base = (size_t)bh * SEQ * HDIM;

    int qrow = qt * 64 + wid * 16 + ml;
    s16x8 qf[2];
    #pragma unroll
    for (int kk = 0; kk < 2; kk++)
        qf[kk] = *(const s16x8*)&q[base + (size_t)qrow * HDIM + kk * 32 + kg];

    f32x4 yacc[4] = {};
    float mrow[4] = {-1e30f, -1e30f, -1e30f, -1e30f};
    float lrow[4] = {};

    int tr = tid >> 2, c0 = (tid & 3) * 16;
    for (int kt = 0; kt <= qt; ++kt) {
        const short* kbp = &kp[base + (size_t)(kt * 64 + tr) * HDIM];
        *(s16x8*)&lds_k[tr * 64 + c0]     = *(const s16x8*)&kbp[c0];
        *(s16x8*)&lds_k[tr * 64 + c0 + 8] = *(const s16x8*)&kbp[c0 + 8];
        const short* vbp = &v[base + (size_t)(kt * 64 + tr) * HDIM];
        s16x8 v0 = *(const s16x8*)&vbp[c0];
        s16x8 v1 = *(const s16x8*)&vbp[c0 + 8];
        #pragma unroll
        for (int j = 0; j < 8; j++) {
            lds_vt[(c0 + j) * 64 + tr]     = v0[j];
            lds_vt[(c0 + 8 + j) * 64 + tr] = v1[j];
        }
        __syncthreads();

        f32x4 s[4] = {};
        #pragma unroll
        for (int ni = 0; ni < 4; ni++)
            #pragma unroll
            for (int kk = 0; kk < 2; kk++) {
                s16x8 bfr = *(const s16x8*)&lds_k[(ni * 16 + ml) * 64 + kk * 32 + kg];
                s[ni] = __builtin_amdgcn_mfma_f32_16x16x32_bf16(qf[kk], bfr, s[ni], 0, 0, 0);
            }
        int qg = qt * 64 + wid * 16 + (lane >> 4) * 4;
        #pragma unroll
        for (int ni = 0; ni < 4; ni++)
            #pragma unroll
            for (int r = 0; r < 4; r++) {
                float fv = s[ni][r] * 0.125f;
                if (kt == qt) {
                    int tg = kt * 64 + ni * 16 + ml;
                    if (tg > qg + r) fv = -1e30f;
                }
                s[ni][r] = fv;
            }
        #pragma unroll
        for (int r = 0; r < 4; r++) {
            float m = fmaxf(fmaxf(s[0][r], s[1][r]), fmaxf(s[2][r], s[3][r]));
            #pragma unroll
            for (int off = 1; off < 16; off <<= 1) m = fmaxf(m, __shfl_xor(m, off));
            float mnew = fmaxf(mrow[r], m);
            float corr = __expf(mrow[r] - mnew);
            mrow[r] = mnew;
            float sum = 0.f;
            #pragma unroll
            for (int ni = 0; ni < 4; ni++) {
                float p = __expf(s[ni][r] - mnew);
                s[ni][r] = p;
                sum += p;
            }
            #pragma unroll
            for (int off = 1; off < 16; off <<= 1) sum += __shfl_xor(sum, off);
            lrow[r] = lrow[r] * corr + sum;
            #pragma unroll
            for (int ni = 0; ni < 4; ni++) yacc[ni][r] *= corr;
        }
        int prow = (lane >> 4) * 4;
        #pragma unroll
        for (int ni = 0; ni < 4; ni++)
            #pragma unroll
            for (int r = 0; r < 4; r++)
                lds_p[wid][(prow + r) * 64 + ni * 16 + ml] = f2bf(s[ni][r]);
        s16x8 pa[2];
        #pragma unroll
        for (int kk = 0; kk < 2; kk++)
            pa[kk] = *(const s16x8*)&lds_p[wid][ml * 64 + kk * 32 + kg];
        #pragma unroll
        for (int ni = 0; ni < 4; ni++)
            #pragma unroll
            for (int kk = 0; kk < 2; kk++) {
                s16x8 vb = *(const s16x8*)&lds_vt[(ni * 16 + ml) * 64 + kk * 32 + kg];
                yacc[ni] = __builtin_amdgcn_mfma_f32_16x16x32_bf16(pa[kk], vb, yacc[ni], 0, 0, 0);
            }
        __syncthreads();
    }

    int b = bh >> 4, h = bh & 15;
    #pragma unroll
    for (int ni = 0; ni < 4; ni++)
        #pragma unroll
        for (int r = 0; r < 4; r++) {
            int t = qt * 64 + wid * 16 + (lane >> 4) * 4 + r;
            float val = yacc[ni][r] / lrow[r];
            y[((size_t)b * SEQ + t) * DMODEL + h * HDIM + ni * 16 + ml] = f2bf(val);
        }
}

// ---------------- launch ----------------
extern "C" void kernel_launch(void* const* d_in, const int* in_sizes, int n_in,
                              void* d_out, int out_size, void* d_ws, size_t ws_size,
                              hipStream_t stream) {
    const float* x_in  = (const float*)d_in[0];
    const float* Wq    = (const float*)d_in[1];
    const float* Wk    = (const float*)d_in[2];
    const float* Wv    = (const float*)d_in[3];
    const float* Wo    = (const float*)d_in[4];
    const float* bq    = (const float*)d_in[5];
    const float* bk    = (const float*)d_in[6];
    const float* bv    = (const float*)d_in[7];
    const float* bo    = (const float*)d_in[8];
    const float* ln1_g = (const float*)d_in[9];
    const float* ln1_b = (const float*)d_in[10];
    const float* ln2_g = (const float*)d_in[11];
    const float* ln2_b = (const float*)d_in[12];
    const float* W1    = (const float*)d_in[13];
    const float* b1    = (const float*)d_in[14];
    const float* W2    = (const float*)d_in[15];
    const float* b2    = (const float*)d_in[16];
    const float* lnf_g = (const float*)d_in[17];
    const float* lnf_b = (const float*)d_in[18];
    const float* Whead = (const float*)d_in[19];

    // activations: x (8MB) | h (4MB) | pool (16MB, mb aliases qkv/y)
    char* wp = (char*)d_ws;
    float* x  = (float*)wp; wp += (size_t)ROWS * DMODEL * 4;
    short* h  = (short*)wp; wp += (size_t)ROWS * DMODEL * 2;
    char* pool = wp;        wp += (size_t)ROWS * FFDIM * 2;
    short* qb = (short*)pool;
    short* kb = (short*)(pool + (size_t)ROWS * DMODEL * 2);
    short* vb = (short*)(pool + (size_t)ROWS * DMODEL * 4);
    short* yb = (short*)(pool + (size_t)ROWS * DMODEL * 6);
    short* mb = (short*)pool;   // [ROWS, FFDIM] — reuses q/k/v/y (dead by FF1)

    const size_t NDD = (size_t)LAYERS * DMODEL * DMODEL;
    const size_t NFD = (size_t)LAYERS * FFDIM * DMODEL;
    const size_t NHD = (size_t)DMODEL * DMODEL;
    size_t act_bytes = (size_t)(wp - (char*)d_ws);
    size_t wb_bytes  = (4 * NDD + 2 * NFD + NHD) * 2;
    bool use_bf = ws_size >= act_bytes + wb_bytes;

    short *wqb=0,*wkb=0,*wvb=0,*wob=0,*w1b=0,*w2b=0,*whb=0;
    if (use_bf) {
        wqb = (short*)wp;  wp += NDD * 2;
        wkb = (short*)wp;  wp += NDD * 2;
        wvb = (short*)wp;  wp += NDD * 2;
        wob = (short*)wp;  wp += NDD * 2;
        w1b = (short*)wp;  wp += NFD * 2;
        w2b = (short*)wp;  wp += NFD * 2;
        whb = (short*)wp;  wp += NHD * 2;
        cvt_kernel<<<(int)(NDD / 2048), 256, 0, stream>>>(Wq, wqb, (int)NDD);
        cvt_kernel<<<(int)(NDD / 2048), 256, 0, stream>>>(Wk, wkb, (int)NDD);
        cvt_kernel<<<(int)(NDD / 2048), 256, 0, stream>>>(Wv, wvb, (int)NDD);
        cvt_kernel<<<(int)(NDD / 2048), 256, 0, stream>>>(Wo, wob, (int)NDD);
        cvt_kernel<<<(int)(NFD / 2048), 256, 0, stream>>>(W1, w1b, (int)NFD);
        cvt_kernel<<<(int)(NFD / 2048), 256, 0, stream>>>(W2, w2b, (int)NFD);
        cvt_kernel<<<(int)(NHD / 2048), 256, 0, stream>>>(Whead, whb, (int)NHD);
    }

    posenc_kernel<<<ROWS * DMODEL / 256, 256, 0, stream>>>(x_in, x);

    for (int l = 0; l < LAYERS; ++l) {
        size_t wdd = (size_t)l * DMODEL * DMODEL;
        size_t wfd = (size_t)l * FFDIM * DMODEL;
        ln_kernel<<<ROWS, 256, 0, stream>>>(x, ln1_g + l * DMODEL, ln1_b + l * DMODEL, h);
        if (use_bf) {
            gemm_bt<EPI_QKV,true><<<dim3(8, 16), 256, 0, stream>>>(h, wqb + wdd, bq + l * DMODEL, nullptr, qb, DMODEL, DMODEL);
            gemm_bt<EPI_QKV,true><<<dim3(8, 16), 256, 0, stream>>>(h, wkb + wdd, bk + l * DMODEL, nullptr, kb, DMODEL, DMODEL);
            gemm_bt<EPI_QKV,true><<<dim3(8, 16), 256, 0, stream>>>(h, wvb + wdd, bv + l * DMODEL, nullptr, vb, DMODEL, DMODEL);
        } else {
            gemm_bt<EPI_QKV,false><<<dim3(8, 16), 256, 0, stream>>>(h, Wq + wdd, bq + l * DMODEL, nullptr, qb, DMODEL, DMODEL);
            gemm_bt<EPI_QKV,false><<<dim3(8, 16), 256, 0, stream>>>(h, Wk + wdd, bk + l * DMODEL, nullptr, kb, DMODEL, DMODEL);
            gemm_bt<EPI_QKV,false><<<dim3(8, 16), 256, 0, stream>>>(h, Wv + wdd, bv + l * DMODEL, nullptr, vb, DMODEL, DMODEL);
        }
        attn_kernel<<<dim3(16, 32), 256, 0, stream>>>(qb, kb, vb, yb);
        if (use_bf) {
            gemm_bt<EPI_RESID,true><<<dim3(8, 16), 256, 0, stream>>>(yb, wob + wdd, bo + l * DMODEL, x, x, DMODEL, DMODEL);
        } else {
            gemm_bt<EPI_RESID,false><<<dim3(8, 16), 256, 0, stream>>>(yb, Wo + wdd, bo + l * DMODEL, x, x, DMODEL, DMODEL);
        }
        ln_kernel<<<ROWS, 256, 0, stream>>>(x, ln2_g + l * DMODEL, ln2_b + l * DMODEL, h);
        if (use_bf) {
            gemm_bt<EPI_GELU,true><<<dim3(32, 16), 256, 0, stream>>>(h, w1b + wfd, b1 + l * FFDIM, nullptr, mb, FFDIM, DMODEL);
            gemm_bt<EPI_RESID,true><<<dim3(8, 16), 256, 0, stream>>>(mb, w2b + wfd, b2 + l * DMODEL, x, x, DMODEL, FFDIM);
        } else {
            gemm_bt<EPI_GELU,false><<<dim3(32, 16), 256, 0, stream>>>(h, W1 + wfd, b1 + l * FFDIM, nullptr, mb, FFDIM, DMODEL);
            gemm_bt<EPI_RESID,false><<<dim3(8, 16), 256, 0, stream>>>(mb, W2 + wfd, b2 + l * DMODEL, x, x, DMODEL, FFDIM);
        }
    }
    ln_kernel<<<ROWS, 256, 0, stream>>>(x, lnf_g, lnf_b, h);
    if (use_bf) {
        gemm_bt<EPI_HEAD,true><<<dim3(8, 16), 256, 0, stream>>>(h, whb, nullptr, nullptr, d_out, DMODEL, DMODEL);
    } else {
        gemm_bt<EPI_HEAD,false><<<dim3(8, 16), 256, 0, stream>>>(h, Whead, nullptr, nullptr, d_out, DMODEL, DMODEL);
    }
}

// Round 7
// 2074.260 us; speedup vs baseline: 1.4639x; 1.4639x over previous
//
#include <hip/hip_runtime.h>
#include <hip/hip_bf16.h>
#include <math.h>

#define LAYERS 8
#define DMODEL 1024
#define NHEAD  16
#define HDIM   64
#define BATCH  2
#define SEQ    1024
#define FFDIM  4096
#define ROWS   (BATCH*SEQ)   // 2048 token rows
#define DD     (DMODEL*DMODEL)

using s16x8 = __attribute__((ext_vector_type(8))) short;
using f32x4 = __attribute__((ext_vector_type(4))) float;

__device__ __forceinline__ short f2bf(float f) {
    union { float f; unsigned u; } v; v.f = f;
    unsigned r = v.u + 0x7fffu + ((v.u >> 16) & 1u);   // RNE
    return (short)(r >> 16);
}

// ---------------- fp32 -> bf16 bulk convert ----------------
__global__ __launch_bounds__(256) void cvt_kernel(const float* __restrict__ in,
                                                  short* __restrict__ out, int n) {
    int i = (blockIdx.x * 256 + threadIdx.x) * 8;
    if (i >= n) return;
    float4 a = *(const float4*)(in + i);
    float4 b = *(const float4*)(in + i + 4);
    s16x8 o;
    o[0]=f2bf(a.x); o[1]=f2bf(a.y); o[2]=f2bf(a.z); o[3]=f2bf(a.w);
    o[4]=f2bf(b.x); o[5]=f2bf(b.y); o[6]=f2bf(b.z); o[7]=f2bf(b.w);
    *(s16x8*)(out + i) = o;
}

// strided convert: src [L][DD] -> dst[l*lstride + off + r]  (for fused QKV weights)
__global__ __launch_bounds__(256) void cvt_str_kernel(const float* __restrict__ in,
                                                      short* __restrict__ out,
                                                      int n, int lstride, int off) {
    int i = (blockIdx.x * 256 + threadIdx.x) * 8;
    if (i >= n) return;
    int l = i / DD, r = i - l * DD;
    float4 a = *(const float4*)(in + i);
    float4 b = *(const float4*)(in + i + 4);
    s16x8 o;
    o[0]=f2bf(a.x); o[1]=f2bf(a.y); o[2]=f2bf(a.z); o[3]=f2bf(a.w);
    o[4]=f2bf(b.x); o[5]=f2bf(b.y); o[6]=f2bf(b.z); o[7]=f2bf(b.w);
    *(s16x8*)(out + (size_t)l * lstride + off + r) = o;
}

// fused bias concat: dst[l][0:1024)=bq[l], [1024:2048)=bk[l], [2048:3072)=bv[l]
__global__ __launch_bounds__(256) void bias_concat_kernel(const float* __restrict__ bq,
                                                          const float* __restrict__ bk,
                                                          const float* __restrict__ bv,
                                                          float* __restrict__ dst) {
    int idx = blockIdx.x * 256 + threadIdx.x;
    if (idx >= LAYERS * 3 * DMODEL) return;
    int l = idx / (3 * DMODEL), j = idx - l * 3 * DMODEL;
    float v;
    if (j < DMODEL)           v = bq[l * DMODEL + j];
    else if (j < 2 * DMODEL)  v = bk[l * DMODEL + j - DMODEL];
    else                      v = bv[l * DMODEL + j - 2 * DMODEL];
    dst[idx] = v;
}

// ---------------- positional encoding ----------------
__global__ __launch_bounds__(256) void posenc_kernel(const float* __restrict__ xin,
                                                     float* __restrict__ xout) {
    int idx = blockIdx.x * 256 + threadIdx.x;
    int d = idx & (DMODEL - 1);
    int t = (idx >> 10) & (SEQ - 1);
    float e = (float)(2 * (d >> 1)) * (1.0f / DMODEL);
    float rate = expf(-e * 9.210340371976184f);
    float a = (float)t * rate;
    float pe = (d & 1) ? cosf(a) : sinf(a);
    xout[idx] = xin[idx] + pe;
}

// ---------------- layernorm ----------------
__global__ __launch_bounds__(256) void ln_kernel(const float* __restrict__ x,
                                                 const float* __restrict__ g,
                                                 const float* __restrict__ b,
                                                 short* __restrict__ out) {
    int row = blockIdx.x;
    const float* xr = x + (size_t)row * DMODEL;
    int tid = threadIdx.x;
    int d = tid * 4;
    float4 v = *(const float4*)&xr[d];
    float s  = v.x + v.y + v.z + v.w;
    float ss = v.x*v.x + v.y*v.y + v.z*v.z + v.w*v.w;
    #pragma unroll
    for (int off = 32; off >= 1; off >>= 1) {
        s  += __shfl_xor(s, off);
        ss += __shfl_xor(ss, off);
    }
    __shared__ float red[8];
    int wid = tid >> 6, lane = tid & 63;
    if (lane == 0) { red[wid] = s; red[4 + wid] = ss; }
    __syncthreads();
    s  = red[0] + red[1] + red[2] + red[3];
    ss = red[4] + red[5] + red[6] + red[7];
    float mu   = s * (1.0f / DMODEL);
    float var  = ss * (1.0f / DMODEL) - mu * mu;
    float rstd = rsqrtf(var + 1e-5f);
    short4 o;
    o.x = f2bf((v.x - mu) * rstd * g[d+0] + b[d+0]);
    o.y = f2bf((v.y - mu) * rstd * g[d+1] + b[d+1]);
    o.z = f2bf((v.z - mu) * rstd * g[d+2] + b[d+2]);
    o.w = f2bf((v.w - mu) * rstd * g[d+3] + b[d+3]);
    *(short4*)&out[(size_t)row * DMODEL + d] = o;
}

// ---------------- GEMM-BT 128x64 tile, 4 waves (wave = 64x32), optional split-K ----------------
// out[M,N] = A[M,K](bf16) . W[N,K]^T + bias
#define EPI_QKV   0
#define EPI_RESID 1
#define EPI_GELU  2
#define EPI_HEAD  3

template<int EPI, bool WBF, int KSPLIT>
__global__ __launch_bounds__(256)
void gemm_bt(const short* __restrict__ A, const void* __restrict__ Wp,
             const float* __restrict__ bias, void* __restrict__ outp,
             int N, int K, int col0) {
    __shared__ short lds_a[128 * 32];
    __shared__ short lds_w[64 * 32];
    int tid  = threadIdx.x;
    int lane = tid & 63, wid = tid >> 6;
    int wr = wid >> 1, wc = wid & 1;                 // wave tile: rows wr*64, cols wc*32
    int ml = lane & 15, kg = (lane >> 4) * 8;
    int m0 = blockIdx.y * 128, n0 = blockIdx.x * 64;
    int Ks = K / KSPLIT, kb = blockIdx.z * Ks;

    f32x4 acc[4][2] = {};

    // staging: A rows tid>>2 (+64), 16B per thread per instr (contiguous per wave)
    int srow = tid >> 2, sq = tid & 3;
    const short* Ab0 = A + (size_t)(m0 + srow) * K + kb + sq * 8;
    const short* Ab1 = Ab0 + (size_t)64 * K;
    short* la0 = &lds_a[tid * 8];
    short* la1 = &lds_a[tid * 8 + 2048];
    short* lw  = &lds_w[tid * 8];
    const short* Wb = WBF ? ((const short*)Wp + (size_t)(n0 + srow) * K + kb + sq * 8) : nullptr;
    const float* Wf = WBF ? nullptr : ((const float*)Wp + (size_t)(n0 + srow) * K + kb + sq * 8);

    int nk = Ks >> 5;
    for (int kt = 0; kt < nk; ++kt) {
        *(s16x8*)la0 = *(const s16x8*)(Ab0 + kt * 32);
        *(s16x8*)la1 = *(const s16x8*)(Ab1 + kt * 32);
        if constexpr (WBF) {
            *(s16x8*)lw = *(const s16x8*)(Wb + kt * 32);
        } else {
            float4 w0 = *(const float4*)(Wf + kt * 32);
            float4 w1 = *(const float4*)(Wf + kt * 32 + 4);
            s16x8 wv;
            wv[0]=f2bf(w0.x); wv[1]=f2bf(w0.y); wv[2]=f2bf(w0.z); wv[3]=f2bf(w0.w);
            wv[4]=f2bf(w1.x); wv[5]=f2bf(w1.y); wv[6]=f2bf(w1.z); wv[7]=f2bf(w1.w);
            *(s16x8*)lw = wv;
        }
        __syncthreads();

        s16x8 af[4], bf[2];
        #pragma unroll
        for (int i = 0; i < 4; i++)
            af[i] = *(const s16x8*)&lds_a[(wr * 64 + i * 16 + ml) * 32 + kg];
        #pragma unroll
        for (int j = 0; j < 2; j++)
            bf[j] = *(const s16x8*)&lds_w[(wc * 32 + j * 16 + ml) * 32 + kg];
        #pragma unroll
        for (int i = 0; i < 4; i++)
            #pragma unroll
            for (int j = 0; j < 2; j++)
                acc[i][j] = __builtin_amdgcn_mfma_f32_16x16x32_bf16(af[i], bf[j], acc[i][j], 0, 0, 0);
        __syncthreads();
    }

    // epilogue (D layout: col=lane&15, row=(lane>>4)*4+reg)
    #pragma unroll
    for (int i = 0; i < 4; i++) {
        #pragma unroll
        for (int j = 0; j < 2; j++) {
            #pragma unroll
            for (int r = 0; r < 4; r++) {
                int row = m0 + wr * 64 + i * 16 + (lane >> 4) * 4 + r;
                int col = n0 + wc * 32 + j * 16 + ml;
                float val = acc[i][j][r];
                if constexpr (EPI == EPI_QKV) {
                    val += bias[col];
                    int gcol = col + col0;
                    int sel = gcol >> 10, cc = gcol & (DMODEL - 1);
                    int hh = cc >> 6, dd = cc & (HDIM - 1);
                    int bb = row >> 10, t = row & (SEQ - 1);
                    ((short*)outp)[(size_t)sel * ROWS * DMODEL +
                                   (((size_t)bb * NHEAD + hh) * SEQ + t) * HDIM + dd] = f2bf(val);
                } else if constexpr (EPI == EPI_RESID) {
                    size_t o = (size_t)row * N + col;
                    if constexpr (KSPLIT == 1) {
                        ((float*)outp)[o] += val + bias[col];
                    } else {
                        float add = val + (blockIdx.z == 0 ? bias[col] : 0.0f);
                        atomicAdd(&((float*)outp)[o], add);
                    }
                } else if constexpr (EPI == EPI_GELU) {
                    val += bias[col];
                    float ge = 0.5f * val * (1.0f + erff(val * 0.70710678118654752f));
                    ((short*)outp)[(size_t)row * N + col] = f2bf(ge);
                } else { // HEAD
                    ((float*)outp)[(size_t)row * N + col] = val;
                }
            }
        }
    }
}

// ---------------- causal flash attention (unchanged) ----------------
__global__ __launch_bounds__(256)
void attn_kernel(const short* __restrict__ q, const short* __restrict__ kp,
                 const short* __restrict__ v, short* __restrict__ y) {
    __shared__ short lds_k[64 * 64];
    __shared__ short lds_vt[64 * 64];
    __shared__ short lds_p[4][16 * 64];
    int tid  = threadIdx.x;
    int lane = tid & 63, wid = tid >> 6;
    int ml = lane & 15, kg = (lane >> 4) * 8;
    int qt = blockIdx.x, bh = blockIdx.y;
    size_t base = (size_t)bh * SEQ * HDIM;

    int qrow = qt * 64 + wid * 16 + ml;
    s16x8 qf[2];
    #pragma unroll
    for (int kk = 0; kk < 2; kk++)
        qf[kk] = *(const s16x8*)&q[base + (size_t)qrow * HDIM + kk * 32 + kg];

    f32x4 yacc[4] = {};
    float mrow[4] = {-1e30f, -1e30f, -1e30f, -1e30f};
    float lrow[4] = {};

    int tr = tid >> 2, c0 = (tid & 3) * 16;
    for (int kt = 0; kt <= qt; ++kt) {
        const short* kbp = &kp[base + (size_t)(kt * 64 + tr) * HDIM];
        *(s16x8*)&lds_k[tr * 64 + c0]     = *(const s16x8*)&kbp[c0];
        *(s16x8*)&lds_k[tr * 64 + c0 + 8] = *(const s16x8*)&kbp[c0 + 8];
        const short* vbp = &v[base + (size_t)(kt * 64 + tr) * HDIM];
        s16x8 v0 = *(const s16x8*)&vbp[c0];
        s16x8 v1 = *(const s16x8*)&vbp[c0 + 8];
        #pragma unroll
        for (int j = 0; j < 8; j++) {
            lds_vt[(c0 + j) * 64 + tr]     = v0[j];
            lds_vt[(c0 + 8 + j) * 64 + tr] = v1[j];
        }
        __syncthreads();

        f32x4 s[4] = {};
        #pragma unroll
        for (int ni = 0; ni < 4; ni++)
            #pragma unroll
            for (int kk = 0; kk < 2; kk++) {
                s16x8 bfr = *(const s16x8*)&lds_k[(ni * 16 + ml) * 64 + kk * 32 + kg];
                s[ni] = __builtin_amdgcn_mfma_f32_16x16x32_bf16(qf[kk], bfr, s[ni], 0, 0, 0);
            }
        int qg = qt * 64 + wid * 16 + (lane >> 4) * 4;
        #pragma unroll
        for (int ni = 0; ni < 4; ni++)
            #pragma unroll
            for (int r = 0; r < 4; r++) {
                float fv = s[ni][r] * 0.125f;
                if (kt == qt) {
                    int tg = kt * 64 + ni * 16 + ml;
                    if (tg > qg + r) fv = -1e30f;
                }
                s[ni][r] = fv;
            }
        #pragma unroll
        for (int r = 0; r < 4; r++) {
            float m = fmaxf(fmaxf(s[0][r], s[1][r]), fmaxf(s[2][r], s[3][r]));
            #pragma unroll
            for (int off = 1; off < 16; off <<= 1) m = fmaxf(m, __shfl_xor(m, off));
            float mnew = fmaxf(mrow[r], m);
            float corr = __expf(mrow[r] - mnew);
            mrow[r] = mnew;
            float sum = 0.f;
            #pragma unroll
            for (int ni = 0; ni < 4; ni++) {
                float p = __expf(s[ni][r] - mnew);
                s[ni][r] = p;
                sum += p;
            }
            #pragma unroll
            for (int off = 1; off < 16; off <<= 1) sum += __shfl_xor(sum, off);
            lrow[r] = lrow[r] * corr + sum;
            #pragma unroll
            for (int ni = 0; ni < 4; ni++) yacc[ni][r] *= corr;
        }
        int prow = (lane >> 4) * 4;
        #pragma unroll
        for (int ni = 0; ni < 4; ni++)
            #pragma unroll
            for (int r = 0; r < 4; r++)
                lds_p[wid][(prow + r) * 64 + ni * 16 + ml] = f2bf(s[ni][r]);
        s16x8 pa[2];
        #pragma unroll
        for (int kk = 0; kk < 2; kk++)
            pa[kk] = *(const s16x8*)&lds_p[wid][ml * 64 + kk * 32 + kg];
        #pragma unroll
        for (int ni = 0; ni < 4; ni++)
            #pragma unroll
            for (int kk = 0; kk < 2; kk++) {
                s16x8 vb = *(const s16x8*)&lds_vt[(ni * 16 + ml) * 64 + kk * 32 + kg];
                yacc[ni] = __builtin_amdgcn_mfma_f32_16x16x32_bf16(pa[kk], vb, yacc[ni], 0, 0, 0);
            }
        __syncthreads();
    }

    int b = bh >> 4, h = bh & 15;
    #pragma unroll
    for (int ni = 0; ni < 4; ni++)
        #pragma unroll
        for (int r = 0; r < 4; r++) {
            int t = qt * 64 + wid * 16 + (lane >> 4) * 4 + r;
            float val = yacc[ni][r] / lrow[r];
            y[((size_t)b * SEQ + t) * DMODEL + h * HDIM + ni * 16 + ml] = f2bf(val);
        }
}

// ---------------- launch ----------------
extern "C" void kernel_launch(void* const* d_in, const int* in_sizes, int n_in,
                              void* d_out, int out_size, void* d_ws, size_t ws_size,
                              hipStream_t stream) {
    const float* x_in  = (const float*)d_in[0];
    const float* Wq    = (const float*)d_in[1];
    const float* Wk    = (const float*)d_in[2];
    const float* Wv    = (const float*)d_in[3];
    const float* Wo    = (const float*)d_in[4];
    const float* bq    = (const float*)d_in[5];
    const float* bk    = (const float*)d_in[6];
    const float* bv    = (const float*)d_in[7];
    const float* bo    = (const float*)d_in[8];
    const float* ln1_g = (const float*)d_in[9];
    const float* ln1_b = (const float*)d_in[10];
    const float* ln2_g = (const float*)d_in[11];
    const float* ln2_b = (const float*)d_in[12];
    const float* W1    = (const float*)d_in[13];
    const float* b1    = (const float*)d_in[14];
    const float* W2    = (const float*)d_in[15];
    const float* b2    = (const float*)d_in[16];
    const float* lnf_g = (const float*)d_in[17];
    const float* lnf_b = (const float*)d_in[18];
    const float* Whead = (const float*)d_in[19];

    // activations: x (8MB) | h (4MB) | pool (16MB, mb aliases q/k/v/y)
    char* wp = (char*)d_ws;
    float* x  = (float*)wp; wp += (size_t)ROWS * DMODEL * 4;
    short* h  = (short*)wp; wp += (size_t)ROWS * DMODEL * 2;
    char* pool = wp;        wp += (size_t)ROWS * FFDIM * 2;
    short* qb = (short*)pool;                                  // q|k|v contiguous
    short* kb = (short*)(pool + (size_t)ROWS * DMODEL * 2);
    short* vb = (short*)(pool + (size_t)ROWS * DMODEL * 4);
    short* yb = (short*)(pool + (size_t)ROWS * DMODEL * 6);
    short* mb = (short*)pool;

    const size_t NDD = (size_t)LAYERS * DD;
    const size_t NFD = (size_t)LAYERS * FFDIM * DMODEL;
    const size_t NHD = (size_t)DD;
    size_t act_bytes = (size_t)(wp - (char*)d_ws);
    size_t wb_bytes  = (3 * NDD + NDD + 2 * NFD + NHD) * 2 + (size_t)LAYERS * 3 * DMODEL * 4;
    bool use_bf = ws_size >= act_bytes + wb_bytes;

    short *wqkvb=0,*wob=0,*w1b=0,*w2b=0,*whb=0; float* bqkv=0;
    if (use_bf) {
        wqkvb = (short*)wp; wp += 3 * NDD * 2;    // [L][3*D][D], q|k|v rows
        wob   = (short*)wp; wp += NDD * 2;
        w1b   = (short*)wp; wp += NFD * 2;
        w2b   = (short*)wp; wp += NFD * 2;
        whb   = (short*)wp; wp += NHD * 2;
        bqkv  = (float*)wp; wp += (size_t)LAYERS * 3 * DMODEL * 4;
        cvt_str_kernel<<<(int)(NDD / 2048), 256, 0, stream>>>(Wq, wqkvb, (int)NDD, 3 * DD, 0);
        cvt_str_kernel<<<(int)(NDD / 2048), 256, 0, stream>>>(Wk, wqkvb, (int)NDD, 3 * DD, DD);
        cvt_str_kernel<<<(int)(NDD / 2048), 256, 0, stream>>>(Wv, wqkvb, (int)NDD, 3 * DD, 2 * DD);
        cvt_kernel<<<(int)(NDD / 2048), 256, 0, stream>>>(Wo, wob, (int)NDD);
        cvt_kernel<<<(int)(NFD / 2048), 256, 0, stream>>>(W1, w1b, (int)NFD);
        cvt_kernel<<<(int)(NFD / 2048), 256, 0, stream>>>(W2, w2b, (int)NFD);
        cvt_kernel<<<(int)(NHD / 2048), 256, 0, stream>>>(Whead, whb, (int)NHD);
        bias_concat_kernel<<<(LAYERS * 3 * DMODEL + 255) / 256, 256, 0, stream>>>(bq, bk, bv, bqkv);
    }

    posenc_kernel<<<ROWS * DMODEL / 256, 256, 0, stream>>>(x_in, x);

    for (int l = 0; l < LAYERS; ++l) {
        size_t wdd = (size_t)l * DD;
        size_t wfd = (size_t)l * FFDIM * DMODEL;
        ln_kernel<<<ROWS, 256, 0, stream>>>(x, ln1_g + l * DMODEL, ln1_b + l * DMODEL, h);
        if (use_bf) {
            gemm_bt<EPI_QKV,true,1><<<dim3(48, 16), 256, 0, stream>>>(
                h, wqkvb + (size_t)l * 3 * DD, bqkv + l * 3 * DMODEL, qb, 3 * DMODEL, DMODEL, 0);
        } else {
            gemm_bt<EPI_QKV,false,1><<<dim3(16, 16), 256, 0, stream>>>(h, Wq + wdd, bq + l * DMODEL, qb, DMODEL, DMODEL, 0);
            gemm_bt<EPI_QKV,false,1><<<dim3(16, 16), 256, 0, stream>>>(h, Wk + wdd, bk + l * DMODEL, qb, DMODEL, DMODEL, 1024);
            gemm_bt<EPI_QKV,false,1><<<dim3(16, 16), 256, 0, stream>>>(h, Wv + wdd, bv + l * DMODEL, qb, DMODEL, DMODEL, 2048);
        }
        attn_kernel<<<dim3(16, 32), 256, 0, stream>>>(qb, kb, vb, yb);
        if (use_bf) {
            gemm_bt<EPI_RESID,true,2><<<dim3(16, 16, 2), 256, 0, stream>>>(yb, wob + wdd, bo + l * DMODEL, x, DMODEL, DMODEL, 0);
        } else {
            gemm_bt<EPI_RESID,false,2><<<dim3(16, 16, 2), 256, 0, stream>>>(yb, Wo + wdd, bo + l * DMODEL, x, DMODEL, DMODEL, 0);
        }
        ln_kernel<<<ROWS, 256, 0, stream>>>(x, ln2_g + l * DMODEL, ln2_b + l * DMODEL, h);
        if (use_bf) {
            gemm_bt<EPI_GELU,true,1><<<dim3(64, 16), 256, 0, stream>>>(h, w1b + wfd, b1 + l * FFDIM, mb, FFDIM, DMODEL, 0);
            gemm_bt<EPI_RESID,true,2><<<dim3(16, 16, 2), 256, 0, stream>>>(mb, w2b + wfd, b2 + l * DMODEL, x, DMODEL, FFDIM, 0);
        } else {
            gemm_bt<EPI_GELU,false,1><<<dim3(64, 16), 256, 0, stream>>>(h, W1 + wfd, b1 + l * FFDIM, mb, FFDIM, DMODEL, 0);
            gemm_bt<EPI_RESID,false,2><<<dim3(16, 16, 2), 256, 0, stream>>>(mb, W2 + wfd, b2 + l * DMODEL, x, DMODEL, FFDIM, 0);
        }
    }
    ln_kernel<<<ROWS, 256, 0, stream>>>(x, lnf_g, lnf_b, h);
    if (use_bf) {
        gemm_bt<EPI_HEAD,true,1><<<dim3(16, 16), 256, 0, stream>>>(h, whb, nullptr, d_out, DMODEL, DMODEL, 0);
    } else {
        gemm_bt<EPI_HEAD,false,1><<<dim3(16, 16), 256, 0, stream>>>(h, Whead, nullptr, d_out, DMODEL, DMODEL, 0);
    }
}